// Round 10
// baseline (1179.016 us; speedup 1.0000x reference)
//
#include <hip/hip_runtime.h>
#include <hip/hip_bf16.h>

#define C_IN  512
#define C_HID 256
#define C_OUT 64
#define K_STEPS 10
#define ALPHA 0.1f

#define BKT_SHIFT 9          // 512 nodes per bucket
#define BKT_NODES 512
#define BCAP 24576           // per-bucket edge capacity (mean 16384 -> huge margin)
#define EPB 4096             // edges per block in pass A (16 per thread)

typedef _Float16 half8 __attribute__((ext_vector_type(8)));
typedef float f32x4 __attribute__((ext_vector_type(4)));

// ---------------------------------------------------------------------------
// CSR build via two-level counting sort (write-locality-friendly)
// ---------------------------------------------------------------------------

__global__ __launch_bounds__(256) void k_bucketA(
    const int* __restrict__ src, const int* __restrict__ dst, int E,
    int* __restrict__ bcursor, long long* __restrict__ bedges, int nbkt)
{
    __shared__ int lcount[256];
    __shared__ int lbase[256];
    int t = threadIdx.x;
    int base = blockIdx.x * EPB;
    for (int i = t; i < nbkt; i += 256) lcount[i] = 0;
    __syncthreads();

    int       mybkt[16];
    int       myoff[16];
    long long mypk[16];
    #pragma unroll
    for (int j = 0; j < 16; j++) {
        int e = base + j * 256 + t;          // coalesced
        if (e < E) {
            int s = src[e], d = dst[e];
            int b = d >> BKT_SHIFT;
            mybkt[j] = b;
            mypk[j]  = ((long long)d << 32) | (unsigned int)s;
            myoff[j] = atomicAdd(&lcount[b], 1);
        } else {
            mybkt[j] = -1;
        }
    }
    __syncthreads();
    for (int i = t; i < nbkt; i += 256)
        lbase[i] = lcount[i] ? atomicAdd(&bcursor[i], lcount[i]) : 0;
    __syncthreads();
    #pragma unroll
    for (int j = 0; j < 16; j++) {
        if (mybkt[j] >= 0) {
            int p = lbase[mybkt[j]] + myoff[j];
            bedges[(size_t)mybkt[j] * BCAP + p] = mypk[j];
        }
    }
}

__global__ __launch_bounds__(256) void k_bcount(
    const int* __restrict__ bcursor, const long long* __restrict__ bedges,
    int* __restrict__ counts, int N)
{
    __shared__ int lcnt[BKT_NODES];
    int b = blockIdx.x, t = threadIdx.x;
    int nodebase = b << BKT_SHIFT;
    for (int i = t; i < BKT_NODES; i += 256) lcnt[i] = 0;
    __syncthreads();
    int cnt = bcursor[b];
    const long long* be = bedges + (size_t)b * BCAP;
    for (int i = t; i < cnt; i += 256) {
        int d = (int)(be[i] >> 32);
        atomicAdd(&lcnt[d - nodebase], 1);
    }
    __syncthreads();
    for (int i = t; i < BKT_NODES; i += 256) {
        int node = nodebase + i;
        if (node < N) counts[node] = lcnt[i];
    }
}

__global__ __launch_bounds__(256) void k_bscatter(
    const int* __restrict__ bcursor, const long long* __restrict__ bedges,
    const int* __restrict__ rowptr, int* __restrict__ csr_src, int N)
{
    __shared__ int lcur[BKT_NODES];
    int b = blockIdx.x, t = threadIdx.x;
    int nodebase = b << BKT_SHIFT;
    for (int i = t; i < BKT_NODES; i += 256) {
        int node = nodebase + i;
        lcur[i] = (node < N) ? rowptr[node] : 0;
    }
    __syncthreads();
    int cnt = bcursor[b];
    const long long* be = bedges + (size_t)b * BCAP;
    for (int i = t; i < cnt; i += 256) {
        long long pk = be[i];
        int d = (int)(pk >> 32);
        int s = (int)pk;
        int p = atomicAdd(&lcur[d - nodebase], 1);
        csr_src[p] = s;
    }
}

// ---------------------------------------------------------------------------
// dinv + rowptr scan
// ---------------------------------------------------------------------------

__global__ void k_dinv(const int* __restrict__ counts, float* __restrict__ dinv, int N) {
    int i = blockIdx.x * blockDim.x + threadIdx.x;
    if (i < N) {
        float deg = (float)(counts[i] + 1);   // +1 self-loop
        dinv[i] = 1.0f / sqrtf(deg);
    }
}

#define SCAN_CHUNK 2048

__global__ void k_scan1(const int* __restrict__ counts, int N, int* __restrict__ bsum) {
    __shared__ int sdata[256];
    int b = blockIdx.x, t = threadIdx.x;
    int base = b * SCAN_CHUNK;
    int sum = 0;
    for (int i = t; i < SCAN_CHUNK; i += 256) {
        int idx = base + i;
        sum += (idx < N) ? counts[idx] : 0;
    }
    sdata[t] = sum;
    __syncthreads();
    for (int off = 128; off; off >>= 1) {
        if (t < off) sdata[t] += sdata[t + off];
        __syncthreads();
    }
    if (t == 0) bsum[b] = sdata[0];
}

__global__ void k_scan2(int* __restrict__ bsum, int nb, int E, int* __restrict__ rowptr, int N) {
    if (blockIdx.x == 0 && threadIdx.x == 0) {
        int run = 0;
        for (int i = 0; i < nb; i++) { int v = bsum[i]; bsum[i] = run; run += v; }
        rowptr[N] = E;
    }
}

__global__ void k_scan3(const int* __restrict__ counts, int N,
                        const int* __restrict__ bsum, int* __restrict__ rowptr) {
    __shared__ int sdata[256];
    int b = blockIdx.x, t = threadIdx.x;
    int base = b * SCAN_CHUNK;
    int vals[8];
    int local = 0;
    #pragma unroll
    for (int i = 0; i < 8; i++) {
        int idx = base + t * 8 + i;
        vals[i] = (idx < N) ? counts[idx] : 0;
        local += vals[i];
    }
    sdata[t] = local;
    __syncthreads();
    for (int off = 1; off < 256; off <<= 1) {
        int y = 0;
        if (t >= off) y = sdata[t - off];
        __syncthreads();
        sdata[t] += y;
        __syncthreads();
    }
    int excl = (t == 0) ? 0 : sdata[t - 1];
    int run = bsum[b] + excl;
    #pragma unroll
    for (int i = 0; i < 8; i++) {
        int idx = base + t * 8 + i;
        if (idx < N) rowptr[idx] = run;
        run += vals[i];
    }
}

// ---------------------------------------------------------------------------
// Weight pre-transpose + f16 conversion: W [K][N] f32 -> Wt [N][K] f16
// ---------------------------------------------------------------------------

__global__ void k_w1t(const float* __restrict__ W, _Float16* __restrict__ Wt) {
    int i = blockIdx.x * 256 + threadIdx.x;          // over 512*256
    int k = i >> 8, n = i & 255;
    Wt[(size_t)n * 512 + k] = (_Float16)W[i];
}

__global__ void k_w2t(const float* __restrict__ W, _Float16* __restrict__ Wt) {
    int i = blockIdx.x * 256 + threadIdx.x;          // over 256*64
    int k = i >> 6, n = i & 63;
    Wt[(size_t)n * 256 + k] = (_Float16)W[i];
}

// ---------------------------------------------------------------------------
// MLP layer 1 (depth-2 counted-vmcnt pipeline): hmid = relu(x @ W1 + b1)
// BM=128, BN=256 (full width -> x read ONCE), BK=32, 16 K-steps.
// 3 x 16KB LDS buffers; stage ks+2 issued each iter; s_waitcnt vmcnt(4)
// (newest stage stays IN FLIGHT across the barrier - T4) + raw s_barrier.
// XOR-swizzled global source / linear LDS dest (m104/m173), swizzled
// ds_read_b128. 4 waves 2x2, each wave 64 rows x 128 cols (acc 4x8).
// ---------------------------------------------------------------------------

__global__ __launch_bounds__(256, 3) void k_mlp1(
    const float* __restrict__ A, const _Float16* __restrict__ Bt,
    const float* __restrict__ bias, _Float16* __restrict__ C, int M)
{
    __shared__ float lds[3][128 * 32];   // 3 x 16KB

    int t    = threadIdx.x;
    int lane = t & 63;
    int wid  = t >> 6;
    int bm   = blockIdx.x * 128;
    int wr   = wid >> 1;                 // wave row (0..1) -> rows 64*wr
    int wc   = wid & 1;                  // wave col (0..1) -> cols 128*wc
    int mrow = lane & 15;
    int kg   = lane >> 4;                // 0..3

    // staging geometry: LDS chunk (q*256 + wid*64 + lane) <- global chunk
    // row r = q*32+wid*8+(lane>>3), pos c = lane&7, src chunk = c ^ (r&7)
    int srow = wid * 8 + (lane >> 3);    // + 32*q
    int cgs  = (lane & 7) ^ (lane >> 3);

    const float* gsrc[4];
    #pragma unroll
    for (int q = 0; q < 4; q++) {
        int gr = bm + q * 32 + srow;
        if (gr >= M) gr = M - 1;         // clamp: no OOB reads, rows discarded at C-write
        gsrc[q] = A + (size_t)gr * 512 + cgs * 4;
    }

    #define STAGE(buf, ks)                                                       \
        {                                                                        \
            _Pragma("unroll")                                                    \
            for (int q = 0; q < 4; q++) {                                        \
                __builtin_amdgcn_global_load_lds(                                \
                    (const __attribute__((address_space(1))) void*)(gsrc[q] + (ks) * 32), \
                    (__attribute__((address_space(3))) void*)((char*)&lds[buf][0] + q * 4096 + wid * 1024), \
                    16, 0, 0);                                                   \
            }                                                                    \
        }

    f32x4 acc[4][8] = {};

    // read-side swizzle: row_local&7 == lane&7 for all mi (offsets mult of 8)
    int m7 = lane & 7;
    int rbase[4];
    #pragma unroll
    for (int mi = 0; mi < 4; mi++)
        rbase[mi] = (wr * 64 + mi * 16 + mrow) * 32;
    int p0 = ((2 * kg) ^ m7) * 4;
    int p1 = ((2 * kg + 1) ^ m7) * 4;

    // prologue: 2 stages in flight
    STAGE(0, 0);
    STAGE(1, 1);

    #pragma unroll
    for (int ks = 0; ks < 16; ks++) {
        // T4: wait for stage ks only; stage ks+1 stays in flight across barrier
        if (ks < 15) {
            asm volatile("s_waitcnt vmcnt(4)" ::: "memory");
        } else {
            asm volatile("s_waitcnt vmcnt(0)" ::: "memory");
        }
        __builtin_amdgcn_s_barrier();
        // all waves are past compute(ks-1) here -> buffer (ks+2)%3 is free
        if (ks < 14) STAGE((ks + 2) % 3, ks + 2);

        const float* lbuf = &lds[ks % 3][0];

        // B fragments direct from L2-resident W1t
        half8 b[8];
        #pragma unroll
        for (int ni = 0; ni < 8; ni++) {
            int n = wc * 128 + ni * 16 + mrow;
            b[ni] = *(const half8*)(Bt + (size_t)n * 512 + ks * 32 + kg * 8);
        }

        // A fragments from LDS (swizzled), convert f32 -> f16
        half8 a[4];
        #pragma unroll
        for (int mi = 0; mi < 4; mi++) {
            f32x4 lo = *(const f32x4*)&lbuf[rbase[mi] + p0];
            f32x4 hi = *(const f32x4*)&lbuf[rbase[mi] + p1];
            a[mi][0] = (_Float16)lo[0]; a[mi][1] = (_Float16)lo[1];
            a[mi][2] = (_Float16)lo[2]; a[mi][3] = (_Float16)lo[3];
            a[mi][4] = (_Float16)hi[0]; a[mi][5] = (_Float16)hi[1];
            a[mi][6] = (_Float16)hi[2]; a[mi][7] = (_Float16)hi[3];
        }

        #pragma unroll
        for (int mi = 0; mi < 4; mi++)
            #pragma unroll
            for (int ni = 0; ni < 8; ni++)
                acc[mi][ni] = __builtin_amdgcn_mfma_f32_16x16x32_f16(
                    a[mi], b[ni], acc[mi][ni], 0, 0, 0);
        // no trailing sync: next iter's vmcnt+barrier closes the reuse window
        // (this iter's ds_reads are consumed by MFMA before that barrier)
    }
    #undef STAGE

    #pragma unroll
    for (int mi = 0; mi < 4; mi++) {
        #pragma unroll
        for (int ni = 0; ni < 8; ni++) {
            int n = wc * 128 + ni * 16 + mrow;
            float bv = bias[n];
            #pragma unroll
            for (int rg = 0; rg < 4; rg++) {
                int row = bm + wr * 64 + mi * 16 + kg * 4 + rg;
                if (row < M) {
                    float v = acc[mi][ni][rg] + bv;
                    C[(size_t)row * 256 + n] = (_Float16)fmaxf(v, 0.f);
                }
            }
        }
    }
}

// ---------------------------------------------------------------------------
// MLP layer 2: h[M][64] f16 = hmid[M][256] f16 @ W2 + b2; also y0 = dinv*h
// ---------------------------------------------------------------------------

__global__ __launch_bounds__(256) void k_mlp2(
    const _Float16* __restrict__ A, const _Float16* __restrict__ Bt,
    const float* __restrict__ bias, const float* __restrict__ dinv,
    _Float16* __restrict__ C, _Float16* __restrict__ Y, int M)
{
    int lane = threadIdx.x & 63;
    int wid  = threadIdx.x >> 6;
    int bm   = blockIdx.x * 256 + wid * 64;
    int mrow = lane & 15;
    int kg   = lane >> 4;
    f32x4 acc[4][4] = {};

    int r[4];
    #pragma unroll
    for (int mi = 0; mi < 4; mi++) {
        int rr = bm + mi * 16 + mrow;
        r[mi] = rr < M ? rr : M - 1;
    }

    for (int k0 = 0; k0 < 256; k0 += 32) {
        int k = k0 + kg * 8;
        half8 a[4], b[4];
        #pragma unroll
        for (int mi = 0; mi < 4; mi++)
            a[mi] = *(const half8*)(A + (size_t)r[mi] * 256 + k);
        #pragma unroll
        for (int ni = 0; ni < 4; ni++) {
            int n = ni * 16 + mrow;
            b[ni] = *(const half8*)(Bt + (size_t)n * 256 + k);
        }
        #pragma unroll
        for (int mi = 0; mi < 4; mi++)
            #pragma unroll
            for (int ni = 0; ni < 4; ni++)
                acc[mi][ni] = __builtin_amdgcn_mfma_f32_16x16x32_f16(
                    a[mi], b[ni], acc[mi][ni], 0, 0, 0);
    }

    #pragma unroll
    for (int mi = 0; mi < 4; mi++) {
        #pragma unroll
        for (int ni = 0; ni < 4; ni++) {
            int n = ni * 16 + mrow;
            float bv = bias[n];
            #pragma unroll
            for (int rg = 0; rg < 4; rg++) {
                int row = bm + mi * 16 + kg * 4 + rg;
                if (row < M) {
                    float v = acc[mi][ni][rg] + bv;
                    C[(size_t)row * 64 + n] = (_Float16)v;
                    Y[(size_t)row * 64 + n] = (_Float16)(v * dinv[row]);
                }
            }
        }
    }
}

// ---------------------------------------------------------------------------
// APPNP propagation on scaled state y = dinv * out (weightless gathers).
// One wave per dst node; 8 lanes per edge (16B each), 8 edges in flight.
// Last iteration fuses log_softmax and writes f32 d_out.
// ---------------------------------------------------------------------------

template <bool LAST>
__global__ __launch_bounds__(256) void k_prop(
    const int* __restrict__ rowptr, const int* __restrict__ csr_src,
    const float* __restrict__ dinv, const _Float16* __restrict__ h,
    const _Float16* __restrict__ ycur, _Float16* __restrict__ ynxt,
    float* __restrict__ out, int N)
{
    int node = blockIdx.x * 4 + (threadIdx.x >> 6);
    if (node >= N) return;
    int lane = threadIdx.x & 63;
    int g  = lane >> 3;       // edge slot 0..7
    int cg = lane & 7;        // channel group: channels [8*cg, 8*cg+8)

    float acc[8] = {};
    int beg = rowptr[node], end = rowptr[node + 1];
    for (int e = beg + g; e < end; e += 8) {
        int s = csr_src[e];
        half8 v = *(const half8*)(ycur + ((size_t)s << 6) + cg * 8);
        #pragma unroll
        for (int c = 0; c < 8; c++) acc[c] += (float)v[c];
    }
    #pragma unroll
    for (int c = 0; c < 8; c++) {
        float a = acc[c];
        a += __shfl_xor(a, 8);
        a += __shfl_xor(a, 16);
        a += __shfl_xor(a, 32);
        acc[c] = a;
    }

    float dn = dinv[node];
    half8 ys = *(const half8*)(ycur + ((size_t)node << 6) + cg * 8);
    half8 hv = *(const half8*)(h    + ((size_t)node << 6) + cg * 8);
    float o[8];
    #pragma unroll
    for (int c = 0; c < 8; c++)
        o[c] = (1.0f - ALPHA) * dn * (acc[c] + (float)ys[c]) + ALPHA * (float)hv[c];

    if (!LAST) {
        if (g == 0) {
            half8 w;
            #pragma unroll
            for (int c = 0; c < 8; c++) w[c] = (_Float16)(dn * o[c]);
            *(half8*)(ynxt + ((size_t)node << 6) + cg * 8) = w;
        }
    } else {
        float m = o[0];
        #pragma unroll
        for (int c = 1; c < 8; c++) m = fmaxf(m, o[c]);
        m = fmaxf(m, __shfl_xor(m, 1));
        m = fmaxf(m, __shfl_xor(m, 2));
        m = fmaxf(m, __shfl_xor(m, 4));
        float s = 0.f;
        #pragma unroll
        for (int c = 0; c < 8; c++) s += __expf(o[c] - m);
        s += __shfl_xor(s, 1);
        s += __shfl_xor(s, 2);
        s += __shfl_xor(s, 4);
        float ls = m + logf(s);
        if (g == 0) {
            f32x4 w0, w1;
            #pragma unroll
            for (int c = 0; c < 4; c++) { w0[c] = o[c] - ls; w1[c] = o[c + 4] - ls; }
            float* p = out + ((size_t)node << 6) + cg * 8;
            *(f32x4*)p = w0;
            *(f32x4*)(p + 4) = w1;
        }
    }
}

// ---------------------------------------------------------------------------
// Launch
// ---------------------------------------------------------------------------

extern "C" void kernel_launch(void* const* d_in, const int* in_sizes, int n_in,
                              void* d_out, int out_size, void* d_ws, size_t ws_size,
                              hipStream_t stream) {
    const float* x  = (const float*)d_in[0];
    const int*   ei = (const int*)d_in[1];
    const float* W1 = (const float*)d_in[2];
    const float* b1 = (const float*)d_in[3];
    const float* W2 = (const float*)d_in[4];
    const float* b2 = (const float*)d_in[5];

    const int N = in_sizes[0] / C_IN;
    const int E = in_sizes[1] / 2;
    const int* src = ei;
    const int* dst = ei + E;

    char* ws = (char*)d_ws;
    size_t off = 0;
    auto alloc = [&](size_t bytes) -> void* {
        void* p = ws + off;
        off += (bytes + 255) & ~(size_t)255;
        return p;
    };

    int nb   = (N + SCAN_CHUNK - 1) / SCAN_CHUNK;
    int nbkt = (N + BKT_NODES - 1) / BKT_NODES;      // 196 for N=100000 (<=256 req'd)

    int*       counts  = (int*)      alloc((size_t)4 * N);
    int*       rowptr  = (int*)      alloc((size_t)4 * (N + 1));
    float*     dinv    = (float*)    alloc((size_t)4 * N);
    int*       bsum    = (int*)      alloc((size_t)4 * (nb + 1));
    int*       bcursor = (int*)      alloc((size_t)4 * nbkt);
    int*       csr_src = (int*)      alloc((size_t)4 * E);
    _Float16*  W1t     = (_Float16*) alloc((size_t)2 * C_IN * C_HID);
    _Float16*  W2t     = (_Float16*) alloc((size_t)2 * C_HID * C_OUT);
    _Float16*  hmid    = (_Float16*) alloc((size_t)2 * N * C_HID);   // 51.2 MB
    _Float16*  h       = (_Float16*) alloc((size_t)2 * N * C_OUT);
    _Float16*  ybuf0   = (_Float16*) alloc((size_t)2 * N * C_OUT);
    _Float16*  ybuf1   = (_Float16*) alloc((size_t)2 * N * C_OUT);
    _Float16*  ybuf2   = (_Float16*) alloc((size_t)2 * N * C_OUT);

    // bedges (nbkt*BCAP*8B = 38.5 MB) aliases hmid (51.2 MB): all bucket
    // passes complete (in-stream) before k_mlp1 writes hmid.
    long long* bedges = (long long*)hmid;

    // --- CSR build: bucket -> count -> scan -> scatter ---
    hipMemsetAsync(bcursor, 0, (size_t)4 * nbkt, stream);
    k_bucketA<<<(E + EPB - 1) / EPB, 256, 0, stream>>>(src, dst, E, bcursor, bedges, nbkt);
    k_bcount<<<nbkt, 256, 0, stream>>>(bcursor, bedges, counts, N);
    k_dinv<<<(N + 255) / 256, 256, 0, stream>>>(counts, dinv, N);
    k_scan1<<<nb, 256, 0, stream>>>(counts, N, bsum);
    k_scan2<<<1, 64, 0, stream>>>(bsum, nb, E, rowptr, N);
    k_scan3<<<nb, 256, 0, stream>>>(counts, N, bsum, rowptr);
    k_bscatter<<<nbkt, 256, 0, stream>>>(bcursor, bedges, rowptr, csr_src, N);

    // --- weight conversion + MLP (f16 MFMA) ---
    k_w1t<<<(C_IN * C_HID) / 256, 256, 0, stream>>>(W1, W1t);
    k_w2t<<<(C_HID * C_OUT) / 256, 256, 0, stream>>>(W2, W2t);
    k_mlp1<<<(N + 127) / 128, 256, 0, stream>>>(x, W1t, b1, hmid, N);
    k_mlp2<<<(N + 255) / 256, 256, 0, stream>>>(hmid, W2t, b2, dinv, h, ybuf0, N);

    // --- propagation on y; last iteration fuses log_softmax ---
    int pgrid = (N + 3) / 4;
    _Float16* ycur = ybuf0;
    for (int it = 0; it < K_STEPS - 1; ++it) {
        _Float16* ynxt = (it & 1) ? ybuf2 : ybuf1;
        k_prop<false><<<pgrid, 256, 0, stream>>>(rowptr, csr_src, dinv, h, ycur, ynxt, nullptr, N);
        ycur = ynxt;
    }
    k_prop<true><<<pgrid, 256, 0, stream>>>(rowptr, csr_src, dinv, h, ycur, nullptr, (float*)d_out, N);
}

// Round 11
// 811.182 us; speedup vs baseline: 1.4535x; 1.4535x over previous
//
#include <hip/hip_runtime.h>
#include <hip/hip_bf16.h>

#define C_IN  512
#define C_HID 256
#define C_OUT 64
#define K_STEPS 10
#define ALPHA 0.1f

#define BKT_SHIFT 9          // 512 nodes per bucket
#define BKT_NODES 512
#define BCAP 24576           // per-bucket edge capacity (mean 16384 -> huge margin)
#define EPB 4096             // edges per block in pass A (16 per thread)

typedef _Float16 half8 __attribute__((ext_vector_type(8)));
typedef float f32x4 __attribute__((ext_vector_type(4)));

// ---------------------------------------------------------------------------
// CSR build via two-level counting sort (write-locality-friendly)
// ---------------------------------------------------------------------------

__global__ __launch_bounds__(256) void k_bucketA(
    const int* __restrict__ src, const int* __restrict__ dst, int E,
    int* __restrict__ bcursor, long long* __restrict__ bedges, int nbkt)
{
    __shared__ int lcount[256];
    __shared__ int lbase[256];
    int t = threadIdx.x;
    int base = blockIdx.x * EPB;
    for (int i = t; i < nbkt; i += 256) lcount[i] = 0;
    __syncthreads();

    int       mybkt[16];
    int       myoff[16];
    long long mypk[16];
    #pragma unroll
    for (int j = 0; j < 16; j++) {
        int e = base + j * 256 + t;          // coalesced
        if (e < E) {
            int s = src[e], d = dst[e];
            int b = d >> BKT_SHIFT;
            mybkt[j] = b;
            mypk[j]  = ((long long)d << 32) | (unsigned int)s;
            myoff[j] = atomicAdd(&lcount[b], 1);
        } else {
            mybkt[j] = -1;
        }
    }
    __syncthreads();
    for (int i = t; i < nbkt; i += 256)
        lbase[i] = lcount[i] ? atomicAdd(&bcursor[i], lcount[i]) : 0;
    __syncthreads();
    #pragma unroll
    for (int j = 0; j < 16; j++) {
        if (mybkt[j] >= 0) {
            int p = lbase[mybkt[j]] + myoff[j];
            bedges[(size_t)mybkt[j] * BCAP + p] = mypk[j];
        }
    }
}

__global__ __launch_bounds__(256) void k_bcount(
    const int* __restrict__ bcursor, const long long* __restrict__ bedges,
    int* __restrict__ counts, int N)
{
    __shared__ int lcnt[BKT_NODES];
    int b = blockIdx.x, t = threadIdx.x;
    int nodebase = b << BKT_SHIFT;
    for (int i = t; i < BKT_NODES; i += 256) lcnt[i] = 0;
    __syncthreads();
    int cnt = bcursor[b];
    const long long* be = bedges + (size_t)b * BCAP;
    for (int i = t; i < cnt; i += 256) {
        int d = (int)(be[i] >> 32);
        atomicAdd(&lcnt[d - nodebase], 1);
    }
    __syncthreads();
    for (int i = t; i < BKT_NODES; i += 256) {
        int node = nodebase + i;
        if (node < N) counts[node] = lcnt[i];
    }
}

__global__ __launch_bounds__(256) void k_bscatter(
    const int* __restrict__ bcursor, const long long* __restrict__ bedges,
    const int* __restrict__ rowptr, int* __restrict__ csr_src, int N)
{
    __shared__ int lcur[BKT_NODES];
    int b = blockIdx.x, t = threadIdx.x;
    int nodebase = b << BKT_SHIFT;
    for (int i = t; i < BKT_NODES; i += 256) {
        int node = nodebase + i;
        lcur[i] = (node < N) ? rowptr[node] : 0;
    }
    __syncthreads();
    int cnt = bcursor[b];
    const long long* be = bedges + (size_t)b * BCAP;
    for (int i = t; i < cnt; i += 256) {
        long long pk = be[i];
        int d = (int)(pk >> 32);
        int s = (int)pk;
        int p = atomicAdd(&lcur[d - nodebase], 1);
        csr_src[p] = s;
    }
}

// ---------------------------------------------------------------------------
// dinv + rowptr scan
// ---------------------------------------------------------------------------

__global__ void k_dinv(const int* __restrict__ counts, float* __restrict__ dinv, int N) {
    int i = blockIdx.x * blockDim.x + threadIdx.x;
    if (i < N) {
        float deg = (float)(counts[i] + 1);   // +1 self-loop
        dinv[i] = 1.0f / sqrtf(deg);
    }
}

#define SCAN_CHUNK 2048

__global__ void k_scan1(const int* __restrict__ counts, int N, int* __restrict__ bsum) {
    __shared__ int sdata[256];
    int b = blockIdx.x, t = threadIdx.x;
    int base = b * SCAN_CHUNK;
    int sum = 0;
    for (int i = t; i < SCAN_CHUNK; i += 256) {
        int idx = base + i;
        sum += (idx < N) ? counts[idx] : 0;
    }
    sdata[t] = sum;
    __syncthreads();
    for (int off = 128; off; off >>= 1) {
        if (t < off) sdata[t] += sdata[t + off];
        __syncthreads();
    }
    if (t == 0) bsum[b] = sdata[0];
}

__global__ void k_scan2(int* __restrict__ bsum, int nb, int E, int* __restrict__ rowptr, int N) {
    if (blockIdx.x == 0 && threadIdx.x == 0) {
        int run = 0;
        for (int i = 0; i < nb; i++) { int v = bsum[i]; bsum[i] = run; run += v; }
        rowptr[N] = E;
    }
}

__global__ void k_scan3(const int* __restrict__ counts, int N,
                        const int* __restrict__ bsum, int* __restrict__ rowptr) {
    __shared__ int sdata[256];
    int b = blockIdx.x, t = threadIdx.x;
    int base = b * SCAN_CHUNK;
    int vals[8];
    int local = 0;
    #pragma unroll
    for (int i = 0; i < 8; i++) {
        int idx = base + t * 8 + i;
        vals[i] = (idx < N) ? counts[idx] : 0;
        local += vals[i];
    }
    sdata[t] = local;
    __syncthreads();
    for (int off = 1; off < 256; off <<= 1) {
        int y = 0;
        if (t >= off) y = sdata[t - off];
        __syncthreads();
        sdata[t] += y;
        __syncthreads();
    }
    int excl = (t == 0) ? 0 : sdata[t - 1];
    int run = bsum[b] + excl;
    #pragma unroll
    for (int i = 0; i < 8; i++) {
        int idx = base + t * 8 + i;
        if (idx < N) rowptr[idx] = run;
        run += vals[i];
    }
}

// ---------------------------------------------------------------------------
// Weight pre-transpose + f16 conversion: W [K][N] f32 -> Wt [N][K] f16
// ---------------------------------------------------------------------------

__global__ void k_w1t(const float* __restrict__ W, _Float16* __restrict__ Wt) {
    int i = blockIdx.x * 256 + threadIdx.x;          // over 512*256
    int k = i >> 8, n = i & 255;
    Wt[(size_t)n * 512 + k] = (_Float16)W[i];
}

__global__ void k_w2t(const float* __restrict__ W, _Float16* __restrict__ Wt) {
    int i = blockIdx.x * 256 + threadIdx.x;          // over 256*64
    int k = i >> 6, n = i & 63;
    Wt[(size_t)n * 256 + k] = (_Float16)W[i];
}

// ---------------------------------------------------------------------------
// MLP layer 1 (2-phase pipelined, ROUND-9 proven config): hmid = relu(x@W1+b1)
// BM=128, BN=256 (full width -> x read ONCE), BK=32, 16 K-steps.
// A staged f32 -> 32KB double-buffered LDS via global_load_lds width=16,
// XOR-swizzled global source / linear LDS dest, swizzled ds_read_b128.
// NOTE: acc[4][8] = 128 AGPRs counts against the unified VGPR budget --
// launch_bounds min-waves MUST stay at 2 (3 forced accumulator spills, r10).
// ---------------------------------------------------------------------------

__global__ __launch_bounds__(256, 2) void k_mlp1(
    const float* __restrict__ A, const _Float16* __restrict__ Bt,
    const float* __restrict__ bias, _Float16* __restrict__ C, int M)
{
    __shared__ float lds[2][128 * 32];   // 2 x 16KB

    int t    = threadIdx.x;
    int lane = t & 63;
    int wid  = t >> 6;
    int bm   = blockIdx.x * 128;
    int wr   = wid >> 1;                 // wave row (0..1) -> rows 64*wr
    int wc   = wid & 1;                  // wave col (0..1) -> cols 128*wc
    int mrow = lane & 15;
    int kg   = lane >> 4;                // 0..3

    // staging geometry: LDS chunk (q*256 + wid*64 + lane) <- global chunk
    // row r = q*32+wid*8+(lane>>3), pos c = lane&7, src chunk = c ^ (r&7)
    int srow = wid * 8 + (lane >> 3);    // + 32*q
    int cgs  = (lane & 7) ^ (lane >> 3);

    const float* gsrc[4];
    #pragma unroll
    for (int q = 0; q < 4; q++) {
        int gr = bm + q * 32 + srow;
        if (gr >= M) gr = M - 1;         // clamp: no OOB reads, rows discarded at C-write
        gsrc[q] = A + (size_t)gr * 512 + cgs * 4;
    }

    #define STAGE(buf, ks)                                                       \
        {                                                                        \
            _Pragma("unroll")                                                    \
            for (int q = 0; q < 4; q++) {                                        \
                __builtin_amdgcn_global_load_lds(                                \
                    (const __attribute__((address_space(1))) void*)(gsrc[q] + (ks) * 32), \
                    (__attribute__((address_space(3))) void*)((char*)&lds[buf][0] + q * 4096 + wid * 1024), \
                    16, 0, 0);                                                   \
            }                                                                    \
        }

    f32x4 acc[4][8] = {};

    // read-side swizzle: row_local&7 == lane&7 for all mi (offsets mult of 8)
    int m7 = lane & 7;
    int rbase[4];
    #pragma unroll
    for (int mi = 0; mi < 4; mi++)
        rbase[mi] = (wr * 64 + mi * 16 + mrow) * 32;
    int p0 = ((2 * kg) ^ m7) * 4;
    int p1 = ((2 * kg + 1) ^ m7) * 4;

    STAGE(0, 0);
    __syncthreads();

    int cur = 0;
    for (int ks = 0; ks < 16; ks++) {
        if (ks < 15) STAGE(cur ^ 1, ks + 1);

        // B fragments direct from L2-resident W1t
        half8 b[8];
        #pragma unroll
        for (int ni = 0; ni < 8; ni++) {
            int n = wc * 128 + ni * 16 + mrow;
            b[ni] = *(const half8*)(Bt + (size_t)n * 512 + ks * 32 + kg * 8);
        }

        // A fragments from LDS (swizzled), convert f32 -> f16
        half8 a[4];
        #pragma unroll
        for (int mi = 0; mi < 4; mi++) {
            f32x4 lo = *(const f32x4*)&lds[cur][rbase[mi] + p0];
            f32x4 hi = *(const f32x4*)&lds[cur][rbase[mi] + p1];
            a[mi][0] = (_Float16)lo[0]; a[mi][1] = (_Float16)lo[1];
            a[mi][2] = (_Float16)lo[2]; a[mi][3] = (_Float16)lo[3];
            a[mi][4] = (_Float16)hi[0]; a[mi][5] = (_Float16)hi[1];
            a[mi][6] = (_Float16)hi[2]; a[mi][7] = (_Float16)hi[3];
        }

        #pragma unroll
        for (int mi = 0; mi < 4; mi++)
            #pragma unroll
            for (int ni = 0; ni < 8; ni++)
                acc[mi][ni] = __builtin_amdgcn_mfma_f32_16x16x32_f16(
                    a[mi], b[ni], acc[mi][ni], 0, 0, 0);

        __syncthreads();   // drains stage(ks+1) + guards buffer reuse
        cur ^= 1;
    }
    #undef STAGE

    #pragma unroll
    for (int mi = 0; mi < 4; mi++) {
        #pragma unroll
        for (int ni = 0; ni < 8; ni++) {
            int n = wc * 128 + ni * 16 + mrow;
            float bv = bias[n];
            #pragma unroll
            for (int rg = 0; rg < 4; rg++) {
                int row = bm + wr * 64 + mi * 16 + kg * 4 + rg;
                if (row < M) {
                    float v = acc[mi][ni][rg] + bv;
                    C[(size_t)row * 256 + n] = (_Float16)fmaxf(v, 0.f);
                }
            }
        }
    }
}

// ---------------------------------------------------------------------------
// MLP layer 2: h[M][64] f16 = hmid[M][256] f16 @ W2 + b2; also y0 = dinv*h
// ---------------------------------------------------------------------------

__global__ __launch_bounds__(256) void k_mlp2(
    const _Float16* __restrict__ A, const _Float16* __restrict__ Bt,
    const float* __restrict__ bias, const float* __restrict__ dinv,
    _Float16* __restrict__ C, _Float16* __restrict__ Y, int M)
{
    int lane = threadIdx.x & 63;
    int wid  = threadIdx.x >> 6;
    int bm   = blockIdx.x * 256 + wid * 64;
    int mrow = lane & 15;
    int kg   = lane >> 4;
    f32x4 acc[4][4] = {};

    int r[4];
    #pragma unroll
    for (int mi = 0; mi < 4; mi++) {
        int rr = bm + mi * 16 + mrow;
        r[mi] = rr < M ? rr : M - 1;
    }

    for (int k0 = 0; k0 < 256; k0 += 32) {
        int k = k0 + kg * 8;
        half8 a[4], b[4];
        #pragma unroll
        for (int mi = 0; mi < 4; mi++)
            a[mi] = *(const half8*)(A + (size_t)r[mi] * 256 + k);
        #pragma unroll
        for (int ni = 0; ni < 4; ni++) {
            int n = ni * 16 + mrow;
            b[ni] = *(const half8*)(Bt + (size_t)n * 256 + k);
        }
        #pragma unroll
        for (int mi = 0; mi < 4; mi++)
            #pragma unroll
            for (int ni = 0; ni < 4; ni++)
                acc[mi][ni] = __builtin_amdgcn_mfma_f32_16x16x32_f16(
                    a[mi], b[ni], acc[mi][ni], 0, 0, 0);
    }

    #pragma unroll
    for (int mi = 0; mi < 4; mi++) {
        #pragma unroll
        for (int ni = 0; ni < 4; ni++) {
            int n = ni * 16 + mrow;
            float bv = bias[n];
            #pragma unroll
            for (int rg = 0; rg < 4; rg++) {
                int row = bm + mi * 16 + kg * 4 + rg;
                if (row < M) {
                    float v = acc[mi][ni][rg] + bv;
                    C[(size_t)row * 64 + n] = (_Float16)v;
                    Y[(size_t)row * 64 + n] = (_Float16)(v * dinv[row]);
                }
            }
        }
    }
}

// ---------------------------------------------------------------------------
// APPNP propagation on scaled state y = dinv * out (weightless gathers).
// One wave per dst node; 8 lanes per edge (16B each), 8 edges in flight,
// UNROLL x4: 4 broadcast index loads then 4 independent 128B gathers per
// iteration (breaks the per-edge index->gather dependent-latency chain).
// Last iteration fuses log_softmax and writes f32 d_out.
// ---------------------------------------------------------------------------

template <bool LAST>
__global__ __launch_bounds__(256) void k_prop(
    const int* __restrict__ rowptr, const int* __restrict__ csr_src,
    const float* __restrict__ dinv, const _Float16* __restrict__ h,
    const _Float16* __restrict__ ycur, _Float16* __restrict__ ynxt,
    float* __restrict__ out, int N)
{
    int node = blockIdx.x * 4 + (threadIdx.x >> 6);
    if (node >= N) return;
    int lane = threadIdx.x & 63;
    int g  = lane >> 3;       // edge slot 0..7
    int cg = lane & 7;        // channel group: channels [8*cg, 8*cg+8)

    int beg = rowptr[node], end = rowptr[node + 1];
    // hoist tail operands so their latency hides under the edge loop
    float dn = dinv[node];
    half8 ys = *(const half8*)(ycur + ((size_t)node << 6) + cg * 8);
    half8 hv = *(const half8*)(h    + ((size_t)node << 6) + cg * 8);

    float acc[8] = {};
    int e = beg + g;
    // main: 32 edges per wave-iteration (4 per slot), all loads independent
    for (; e + 24 < end; e += 32) {
        int s0 = csr_src[e];
        int s1 = csr_src[e + 8];
        int s2 = csr_src[e + 16];
        int s3 = csr_src[e + 24];
        half8 v0 = *(const half8*)(ycur + ((size_t)s0 << 6) + cg * 8);
        half8 v1 = *(const half8*)(ycur + ((size_t)s1 << 6) + cg * 8);
        half8 v2 = *(const half8*)(ycur + ((size_t)s2 << 6) + cg * 8);
        half8 v3 = *(const half8*)(ycur + ((size_t)s3 << 6) + cg * 8);
        #pragma unroll
        for (int c = 0; c < 8; c++)
            acc[c] += ((float)v0[c] + (float)v1[c]) + ((float)v2[c] + (float)v3[c]);
    }
    // tail: 8 edges per iteration
    for (; e < end; e += 8) {
        int s = csr_src[e];
        half8 v = *(const half8*)(ycur + ((size_t)s << 6) + cg * 8);
        #pragma unroll
        for (int c = 0; c < 8; c++) acc[c] += (float)v[c];
    }

    // reduce the 8 edge slots
    #pragma unroll
    for (int c = 0; c < 8; c++) {
        float a = acc[c];
        a += __shfl_xor(a, 8);
        a += __shfl_xor(a, 16);
        a += __shfl_xor(a, 32);
        acc[c] = a;
    }

    float o[8];
    #pragma unroll
    for (int c = 0; c < 8; c++)
        o[c] = (1.0f - ALPHA) * dn * (acc[c] + (float)ys[c]) + ALPHA * (float)hv[c];

    if (!LAST) {
        if (g == 0) {
            half8 w;
            #pragma unroll
            for (int c = 0; c < 8; c++) w[c] = (_Float16)(dn * o[c]);
            *(half8*)(ynxt + ((size_t)node << 6) + cg * 8) = w;
        }
    } else {
        float m = o[0];
        #pragma unroll
        for (int c = 1; c < 8; c++) m = fmaxf(m, o[c]);
        m = fmaxf(m, __shfl_xor(m, 1));
        m = fmaxf(m, __shfl_xor(m, 2));
        m = fmaxf(m, __shfl_xor(m, 4));
        float s = 0.f;
        #pragma unroll
        for (int c = 0; c < 8; c++) s += __expf(o[c] - m);
        s += __shfl_xor(s, 1);
        s += __shfl_xor(s, 2);
        s += __shfl_xor(s, 4);
        float ls = m + logf(s);
        if (g == 0) {
            f32x4 w0, w1;
            #pragma unroll
            for (int c = 0; c < 4; c++) { w0[c] = o[c] - ls; w1[c] = o[c + 4] - ls; }
            float* p = out + ((size_t)node << 6) + cg * 8;
            *(f32x4*)p = w0;
            *(f32x4*)(p + 4) = w1;
        }
    }
}

// ---------------------------------------------------------------------------
// Launch
// ---------------------------------------------------------------------------

extern "C" void kernel_launch(void* const* d_in, const int* in_sizes, int n_in,
                              void* d_out, int out_size, void* d_ws, size_t ws_size,
                              hipStream_t stream) {
    const float* x  = (const float*)d_in[0];
    const int*   ei = (const int*)d_in[1];
    const float* W1 = (const float*)d_in[2];
    const float* b1 = (const float*)d_in[3];
    const float* W2 = (const float*)d_in[4];
    const float* b2 = (const float*)d_in[5];

    const int N = in_sizes[0] / C_IN;
    const int E = in_sizes[1] / 2;
    const int* src = ei;
    const int* dst = ei + E;

    char* ws = (char*)d_ws;
    size_t off = 0;
    auto alloc = [&](size_t bytes) -> void* {
        void* p = ws + off;
        off += (bytes + 255) & ~(size_t)255;
        return p;
    };

    int nb   = (N + SCAN_CHUNK - 1) / SCAN_CHUNK;
    int nbkt = (N + BKT_NODES - 1) / BKT_NODES;      // 196 for N=100000 (<=256 req'd)

    int*       counts  = (int*)      alloc((size_t)4 * N);
    int*       rowptr  = (int*)      alloc((size_t)4 * (N + 1));
    float*     dinv    = (float*)    alloc((size_t)4 * N);
    int*       bsum    = (int*)      alloc((size_t)4 * (nb + 1));
    int*       bcursor = (int*)      alloc((size_t)4 * nbkt);
    int*       csr_src = (int*)      alloc((size_t)4 * E);
    _Float16*  W1t     = (_Float16*) alloc((size_t)2 * C_IN * C_HID);
    _Float16*  W2t     = (_Float16*) alloc((size_t)2 * C_HID * C_OUT);
    _Float16*  hmid    = (_Float16*) alloc((size_t)2 * N * C_HID);   // 51.2 MB
    _Float16*  h       = (_Float16*) alloc((size_t)2 * N * C_OUT);
    _Float16*  ybuf0   = (_Float16*) alloc((size_t)2 * N * C_OUT);
    _Float16*  ybuf1   = (_Float16*) alloc((size_t)2 * N * C_OUT);
    _Float16*  ybuf2   = (_Float16*) alloc((size_t)2 * N * C_OUT);

    // bedges (nbkt*BCAP*8B = 38.5 MB) aliases hmid (51.2 MB): all bucket
    // passes complete (in-stream) before k_mlp1 writes hmid.
    long long* bedges = (long long*)hmid;

    // --- CSR build: bucket -> count -> scan -> scatter ---
    hipMemsetAsync(bcursor, 0, (size_t)4 * nbkt, stream);
    k_bucketA<<<(E + EPB - 1) / EPB, 256, 0, stream>>>(src, dst, E, bcursor, bedges, nbkt);
    k_bcount<<<nbkt, 256, 0, stream>>>(bcursor, bedges, counts, N);
    k_dinv<<<(N + 255) / 256, 256, 0, stream>>>(counts, dinv, N);
    k_scan1<<<nb, 256, 0, stream>>>(counts, N, bsum);
    k_scan2<<<1, 64, 0, stream>>>(bsum, nb, E, rowptr, N);
    k_scan3<<<nb, 256, 0, stream>>>(counts, N, bsum, rowptr);
    k_bscatter<<<nbkt, 256, 0, stream>>>(bcursor, bedges, rowptr, csr_src, N);

    // --- weight conversion + MLP (f16 MFMA) ---
    k_w1t<<<(C_IN * C_HID) / 256, 256, 0, stream>>>(W1, W1t);
    k_w2t<<<(C_HID * C_OUT) / 256, 256, 0, stream>>>(W2, W2t);
    k_mlp1<<<(N + 127) / 128, 256, 0, stream>>>(x, W1t, b1, hmid, N);
    k_mlp2<<<(N + 255) / 256, 256, 0, stream>>>(hmid, W2t, b2, dinv, h, ybuf0, N);

    // --- propagation on y; last iteration fuses log_softmax ---
    int pgrid = (N + 3) / 4;
    _Float16* ycur = ybuf0;
    for (int it = 0; it < K_STEPS - 1; ++it) {
        _Float16* ynxt = (it & 1) ? ybuf2 : ybuf1;
        k_prop<false><<<pgrid, 256, 0, stream>>>(rowptr, csr_src, dinv, h, ycur, ynxt, nullptr, N);
        ycur = ynxt;
    }
    k_prop<true><<<pgrid, 256, 0, stream>>>(rowptr, csr_src, dinv, h, ycur, nullptr, (float*)d_out, N);
}

// Round 12
// 773.187 us; speedup vs baseline: 1.5249x; 1.0491x over previous
//
#include <hip/hip_runtime.h>
#include <hip/hip_bf16.h>

#define C_IN  512
#define C_HID 256
#define C_OUT 64
#define K_STEPS 10
#define ALPHA 0.1f

#define BKT_SHIFT 9          // 512 nodes per bucket
#define BKT_NODES 512
#define BCAP 24576           // per-bucket edge capacity (mean 16384 -> huge margin)
#define EPB 4096             // edges per block in pass A (16 per thread)

typedef _Float16 half8 __attribute__((ext_vector_type(8)));
typedef float f32x4 __attribute__((ext_vector_type(4)));

// ---------------------------------------------------------------------------
// CSR build via two-level counting sort (write-locality-friendly)
// ---------------------------------------------------------------------------

__global__ __launch_bounds__(256) void k_bucketA(
    const int* __restrict__ src, const int* __restrict__ dst, int E,
    int* __restrict__ bcursor, long long* __restrict__ bedges, int nbkt)
{
    __shared__ int lcount[256];
    __shared__ int lbase[256];
    int t = threadIdx.x;
    int base = blockIdx.x * EPB;
    for (int i = t; i < nbkt; i += 256) lcount[i] = 0;
    __syncthreads();

    int       mybkt[16];
    int       myoff[16];
    long long mypk[16];
    #pragma unroll
    for (int j = 0; j < 16; j++) {
        int e = base + j * 256 + t;          // coalesced
        if (e < E) {
            int s = src[e], d = dst[e];
            int b = d >> BKT_SHIFT;
            mybkt[j] = b;
            mypk[j]  = ((long long)d << 32) | (unsigned int)s;
            myoff[j] = atomicAdd(&lcount[b], 1);
        } else {
            mybkt[j] = -1;
        }
    }
    __syncthreads();
    for (int i = t; i < nbkt; i += 256)
        lbase[i] = lcount[i] ? atomicAdd(&bcursor[i], lcount[i]) : 0;
    __syncthreads();
    #pragma unroll
    for (int j = 0; j < 16; j++) {
        if (mybkt[j] >= 0) {
            int p = lbase[mybkt[j]] + myoff[j];
            bedges[(size_t)mybkt[j] * BCAP + p] = mypk[j];
        }
    }
}

__global__ __launch_bounds__(256) void k_bcount(
    const int* __restrict__ bcursor, const long long* __restrict__ bedges,
    int* __restrict__ counts, int N)
{
    __shared__ int lcnt[BKT_NODES];
    int b = blockIdx.x, t = threadIdx.x;
    int nodebase = b << BKT_SHIFT;
    for (int i = t; i < BKT_NODES; i += 256) lcnt[i] = 0;
    __syncthreads();
    int cnt = bcursor[b];
    const long long* be = bedges + (size_t)b * BCAP;
    for (int i = t; i < cnt; i += 256) {
        int d = (int)(be[i] >> 32);
        atomicAdd(&lcnt[d - nodebase], 1);
    }
    __syncthreads();
    for (int i = t; i < BKT_NODES; i += 256) {
        int node = nodebase + i;
        if (node < N) counts[node] = lcnt[i];
    }
}

__global__ __launch_bounds__(256) void k_bscatter(
    const int* __restrict__ bcursor, const long long* __restrict__ bedges,
    const int* __restrict__ rowptr, int* __restrict__ csr_src, int N)
{
    __shared__ int lcur[BKT_NODES];
    int b = blockIdx.x, t = threadIdx.x;
    int nodebase = b << BKT_SHIFT;
    for (int i = t; i < BKT_NODES; i += 256) {
        int node = nodebase + i;
        lcur[i] = (node < N) ? rowptr[node] : 0;
    }
    __syncthreads();
    int cnt = bcursor[b];
    const long long* be = bedges + (size_t)b * BCAP;
    for (int i = t; i < cnt; i += 256) {
        long long pk = be[i];
        int d = (int)(pk >> 32);
        int s = (int)pk;
        int p = atomicAdd(&lcur[d - nodebase], 1);
        csr_src[p] = s;
    }
}

// ---------------------------------------------------------------------------
// dinv + rowptr scan
// ---------------------------------------------------------------------------

__global__ void k_dinv(const int* __restrict__ counts, float* __restrict__ dinv, int N) {
    int i = blockIdx.x * blockDim.x + threadIdx.x;
    if (i < N) {
        float deg = (float)(counts[i] + 1);   // +1 self-loop
        dinv[i] = 1.0f / sqrtf(deg);
    }
}

#define SCAN_CHUNK 2048

__global__ void k_scan1(const int* __restrict__ counts, int N, int* __restrict__ bsum) {
    __shared__ int sdata[256];
    int b = blockIdx.x, t = threadIdx.x;
    int base = b * SCAN_CHUNK;
    int sum = 0;
    for (int i = t; i < SCAN_CHUNK; i += 256) {
        int idx = base + i;
        sum += (idx < N) ? counts[idx] : 0;
    }
    sdata[t] = sum;
    __syncthreads();
    for (int off = 128; off; off >>= 1) {
        if (t < off) sdata[t] += sdata[t + off];
        __syncthreads();
    }
    if (t == 0) bsum[b] = sdata[0];
}

__global__ void k_scan2(int* __restrict__ bsum, int nb, int E, int* __restrict__ rowptr, int N) {
    if (blockIdx.x == 0 && threadIdx.x == 0) {
        int run = 0;
        for (int i = 0; i < nb; i++) { int v = bsum[i]; bsum[i] = run; run += v; }
        rowptr[N] = E;
    }
}

__global__ void k_scan3(const int* __restrict__ counts, int N,
                        const int* __restrict__ bsum, int* __restrict__ rowptr) {
    __shared__ int sdata[256];
    int b = blockIdx.x, t = threadIdx.x;
    int base = b * SCAN_CHUNK;
    int vals[8];
    int local = 0;
    #pragma unroll
    for (int i = 0; i < 8; i++) {
        int idx = base + t * 8 + i;
        vals[i] = (idx < N) ? counts[idx] : 0;
        local += vals[i];
    }
    sdata[t] = local;
    __syncthreads();
    for (int off = 1; off < 256; off <<= 1) {
        int y = 0;
        if (t >= off) y = sdata[t - off];
        __syncthreads();
        sdata[t] += y;
        __syncthreads();
    }
    int excl = (t == 0) ? 0 : sdata[t - 1];
    int run = bsum[b] + excl;
    #pragma unroll
    for (int i = 0; i < 8; i++) {
        int idx = base + t * 8 + i;
        if (idx < N) rowptr[idx] = run;
        run += vals[i];
    }
}

// ---------------------------------------------------------------------------
// Weight pre-transpose + f16 conversion: W [K][N] f32 -> Wt [N][K] f16
// ---------------------------------------------------------------------------

__global__ void k_w1t(const float* __restrict__ W, _Float16* __restrict__ Wt) {
    int i = blockIdx.x * 256 + threadIdx.x;          // over 512*256
    int k = i >> 8, n = i & 255;
    Wt[(size_t)n * 512 + k] = (_Float16)W[i];
}

__global__ void k_w2t(const float* __restrict__ W, _Float16* __restrict__ Wt) {
    int i = blockIdx.x * 256 + threadIdx.x;          // over 256*64
    int k = i >> 6, n = i & 63;
    Wt[(size_t)n * 256 + k] = (_Float16)W[i];
}

// ---------------------------------------------------------------------------
// MLP layer 1 (counted-vmcnt depth-2 pipeline, NO launch-bounds squeeze):
// hmid = relu(x @ W1 + b1). BM=128, BN=256 (x read ONCE), BK=32, 16 K-steps.
// 3 x 16KB LDS buffers. Per iter: vmcnt(4)+lgkmcnt(0) fence, s_barrier,
// B loads FIRST (so compiler's B-use wait vmcnt(4) drains stage t(ks) but
// keeps the newest stage in flight -- vmcnt completes in issue order), then
// STAGE t(ks+2). The iter-top vmcnt(4) is the hard tile-ready guarantee.
// launch_bounds MUST stay (256,2): acc[4][8]=128 AGPRs on the unified file;
// (256,3) spilled accumulators to scratch (r10: 1.12GB hbm_bytes, 3x slower).
// ---------------------------------------------------------------------------

__global__ __launch_bounds__(256, 2) void k_mlp1(
    const float* __restrict__ A, const _Float16* __restrict__ Bt,
    const float* __restrict__ bias, _Float16* __restrict__ C, int M)
{
    __shared__ float lds[3][128 * 32];   // 3 x 16KB

    int t    = threadIdx.x;
    int lane = t & 63;
    int wid  = t >> 6;
    int bm   = blockIdx.x * 128;
    int wr   = wid >> 1;                 // wave row (0..1) -> rows 64*wr
    int wc   = wid & 1;                  // wave col (0..1) -> cols 128*wc
    int mrow = lane & 15;
    int kg   = lane >> 4;                // 0..3

    // staging geometry: LDS chunk (q*256 + wid*64 + lane) <- global chunk
    // row r = q*32+wid*8+(lane>>3), pos c = lane&7, src chunk = c ^ (r&7)
    int srow = wid * 8 + (lane >> 3);    // + 32*q
    int cgs  = (lane & 7) ^ (lane >> 3);

    const float* gsrc[4];
    #pragma unroll
    for (int q = 0; q < 4; q++) {
        int gr = bm + q * 32 + srow;
        if (gr >= M) gr = M - 1;         // clamp: no OOB reads, rows discarded at C-write
        gsrc[q] = A + (size_t)gr * 512 + cgs * 4;
    }

    #define STAGE(buf, ks)                                                       \
        {                                                                        \
            _Pragma("unroll")                                                    \
            for (int q = 0; q < 4; q++) {                                        \
                __builtin_amdgcn_global_load_lds(                                \
                    (const __attribute__((address_space(1))) void*)(gsrc[q] + (ks) * 32), \
                    (__attribute__((address_space(3))) void*)((char*)&lds[buf][0] + q * 4096 + wid * 1024), \
                    16, 0, 0);                                                   \
            }                                                                    \
        }

    f32x4 acc[4][8] = {};

    // read-side swizzle: row_local&7 == lane&7 for all mi (offsets mult of 8)
    int m7 = lane & 7;
    int rbase[4];
    #pragma unroll
    for (int mi = 0; mi < 4; mi++)
        rbase[mi] = (wr * 64 + mi * 16 + mrow) * 32;
    int p0 = ((2 * kg) ^ m7) * 4;
    int p1 = ((2 * kg + 1) ^ m7) * 4;

    // prologue: 2 stages in flight
    STAGE(0, 0);
    STAGE(1, 1);

    #pragma unroll
    for (int ks = 0; ks < 16; ks++) {
        // hard guarantee: newest-4 outstanding = latest stage; waiting to 4
        // drains everything older, incl. tile ks. lgkmcnt(0) closes the
        // prior-iter ds_read vs DMA-overwrite window before the barrier.
        asm volatile("s_waitcnt vmcnt(4) lgkmcnt(0)" ::: "memory");
        __builtin_amdgcn_s_barrier();

        // B loads FIRST (older than the stage issued below -> compiler's
        // pre-MFMA wait for B leaves the newest stage in flight)
        half8 b[8];
        #pragma unroll
        for (int ni = 0; ni < 8; ni++) {
            int n = wc * 128 + ni * 16 + mrow;
            b[ni] = *(const half8*)(Bt + (size_t)n * 512 + ks * 32 + kg * 8);
        }

        if (ks < 14) STAGE((ks + 2) % 3, ks + 2);

        const float* lbuf = &lds[ks % 3][0];

        // A fragments from LDS (swizzled), convert f32 -> f16
        half8 a[4];
        #pragma unroll
        for (int mi = 0; mi < 4; mi++) {
            f32x4 lo = *(const f32x4*)&lbuf[rbase[mi] + p0];
            f32x4 hi = *(const f32x4*)&lbuf[rbase[mi] + p1];
            a[mi][0] = (_Float16)lo[0]; a[mi][1] = (_Float16)lo[1];
            a[mi][2] = (_Float16)lo[2]; a[mi][3] = (_Float16)lo[3];
            a[mi][4] = (_Float16)hi[0]; a[mi][5] = (_Float16)hi[1];
            a[mi][6] = (_Float16)hi[2]; a[mi][7] = (_Float16)hi[3];
        }

        #pragma unroll
        for (int mi = 0; mi < 4; mi++)
            #pragma unroll
            for (int ni = 0; ni < 8; ni++)
                acc[mi][ni] = __builtin_amdgcn_mfma_f32_16x16x32_f16(
                    a[mi], b[ni], acc[mi][ni], 0, 0, 0);
    }
    #undef STAGE

    #pragma unroll
    for (int mi = 0; mi < 4; mi++) {
        #pragma unroll
        for (int ni = 0; ni < 8; ni++) {
            int n = wc * 128 + ni * 16 + mrow;
            float bv = bias[n];
            #pragma unroll
            for (int rg = 0; rg < 4; rg++) {
                int row = bm + wr * 64 + mi * 16 + kg * 4 + rg;
                if (row < M) {
                    float v = acc[mi][ni][rg] + bv;
                    C[(size_t)row * 256 + n] = (_Float16)fmaxf(v, 0.f);
                }
            }
        }
    }
}

// ---------------------------------------------------------------------------
// MLP layer 2: h[M][64] f16 = hmid[M][256] f16 @ W2 + b2; also y0 = dinv*h
// ---------------------------------------------------------------------------

__global__ __launch_bounds__(256) void k_mlp2(
    const _Float16* __restrict__ A, const _Float16* __restrict__ Bt,
    const float* __restrict__ bias, const float* __restrict__ dinv,
    _Float16* __restrict__ C, _Float16* __restrict__ Y, int M)
{
    int lane = threadIdx.x & 63;
    int wid  = threadIdx.x >> 6;
    int bm   = blockIdx.x * 256 + wid * 64;
    int mrow = lane & 15;
    int kg   = lane >> 4;
    f32x4 acc[4][4] = {};

    int r[4];
    #pragma unroll
    for (int mi = 0; mi < 4; mi++) {
        int rr = bm + mi * 16 + mrow;
        r[mi] = rr < M ? rr : M - 1;
    }

    for (int k0 = 0; k0 < 256; k0 += 32) {
        int k = k0 + kg * 8;
        half8 a[4], b[4];
        #pragma unroll
        for (int mi = 0; mi < 4; mi++)
            a[mi] = *(const half8*)(A + (size_t)r[mi] * 256 + k);
        #pragma unroll
        for (int ni = 0; ni < 4; ni++) {
            int n = ni * 16 + mrow;
            b[ni] = *(const half8*)(Bt + (size_t)n * 256 + k);
        }
        #pragma unroll
        for (int mi = 0; mi < 4; mi++)
            #pragma unroll
            for (int ni = 0; ni < 4; ni++)
                acc[mi][ni] = __builtin_amdgcn_mfma_f32_16x16x32_f16(
                    a[mi], b[ni], acc[mi][ni], 0, 0, 0);
    }

    #pragma unroll
    for (int mi = 0; mi < 4; mi++) {
        #pragma unroll
        for (int ni = 0; ni < 4; ni++) {
            int n = ni * 16 + mrow;
            float bv = bias[n];
            #pragma unroll
            for (int rg = 0; rg < 4; rg++) {
                int row = bm + mi * 16 + kg * 4 + rg;
                if (row < M) {
                    float v = acc[mi][ni][rg] + bv;
                    C[(size_t)row * 64 + n] = (_Float16)v;
                    Y[(size_t)row * 64 + n] = (_Float16)(v * dinv[row]);
                }
            }
        }
    }
}

// ---------------------------------------------------------------------------
// APPNP propagation on scaled state y = dinv * out (weightless gathers).
// One wave per dst node; 8 lanes per edge (16B each). Single MASKED 32-edge
// pass per iteration (clamped index + 0/1-weighted add): all 4 gathers always
// in flight, no serial 8-edge tail chain (deg ~ Poisson(32)).
// Last iteration fuses log_softmax and writes f32 d_out.
// ---------------------------------------------------------------------------

template <bool LAST>
__global__ __launch_bounds__(256) void k_prop(
    const int* __restrict__ rowptr, const int* __restrict__ csr_src,
    const float* __restrict__ dinv, const _Float16* __restrict__ h,
    const _Float16* __restrict__ ycur, _Float16* __restrict__ ynxt,
    float* __restrict__ out, int N)
{
    int node = blockIdx.x * 4 + (threadIdx.x >> 6);
    if (node >= N) return;
    int lane = threadIdx.x & 63;
    int g  = lane >> 3;       // edge slot 0..7
    int cg = lane & 7;        // channel group: channels [8*cg, 8*cg+8)

    int beg = rowptr[node], end = rowptr[node + 1];
    // hoist tail operands so their latency hides under the edge loop
    float dn = dinv[node];
    half8 ys = *(const half8*)(ycur + ((size_t)node << 6) + cg * 8);
    half8 hv = *(const half8*)(h    + ((size_t)node << 6) + cg * 8);

    float acc[8] = {};
    for (int e = beg + g; e < end; e += 32) {
        int i1 = e + 8, i2 = e + 16, i3 = e + 24;
        float p1 = (i1 < end) ? 1.f : 0.f;
        float p2 = (i2 < end) ? 1.f : 0.f;
        float p3 = (i3 < end) ? 1.f : 0.f;
        int s0 = csr_src[e];
        int s1 = csr_src[(i1 < end) ? i1 : e];
        int s2 = csr_src[(i2 < end) ? i2 : e];
        int s3 = csr_src[(i3 < end) ? i3 : e];
        half8 v0 = *(const half8*)(ycur + ((size_t)s0 << 6) + cg * 8);
        half8 v1 = *(const half8*)(ycur + ((size_t)s1 << 6) + cg * 8);
        half8 v2 = *(const half8*)(ycur + ((size_t)s2 << 6) + cg * 8);
        half8 v3 = *(const half8*)(ycur + ((size_t)s3 << 6) + cg * 8);
        #pragma unroll
        for (int c = 0; c < 8; c++)
            acc[c] += ((float)v0[c] + p1 * (float)v1[c])
                    + (p2 * (float)v2[c] + p3 * (float)v3[c]);
    }

    // reduce the 8 edge slots
    #pragma unroll
    for (int c = 0; c < 8; c++) {
        float a = acc[c];
        a += __shfl_xor(a, 8);
        a += __shfl_xor(a, 16);
        a += __shfl_xor(a, 32);
        acc[c] = a;
    }

    float o[8];
    #pragma unroll
    for (int c = 0; c < 8; c++)
        o[c] = (1.0f - ALPHA) * dn * (acc[c] + (float)ys[c]) + ALPHA * (float)hv[c];

    if (!LAST) {
        if (g == 0) {
            half8 w;
            #pragma unroll
            for (int c = 0; c < 8; c++) w[c] = (_Float16)(dn * o[c]);
            *(half8*)(ynxt + ((size_t)node << 6) + cg * 8) = w;
        }
    } else {
        float m = o[0];
        #pragma unroll
        for (int c = 1; c < 8; c++) m = fmaxf(m, o[c]);
        m = fmaxf(m, __shfl_xor(m, 1));
        m = fmaxf(m, __shfl_xor(m, 2));
        m = fmaxf(m, __shfl_xor(m, 4));
        float s = 0.f;
        #pragma unroll
        for (int c = 0; c < 8; c++) s += __expf(o[c] - m);
        s += __shfl_xor(s, 1);
        s += __shfl_xor(s, 2);
        s += __shfl_xor(s, 4);
        float ls = m + logf(s);
        if (g == 0) {
            f32x4 w0, w1;
            #pragma unroll
            for (int c = 0; c < 4; c++) { w0[c] = o[c] - ls; w1[c] = o[c + 4] - ls; }
            float* p = out + ((size_t)node << 6) + cg * 8;
            *(f32x4*)p = w0;
            *(f32x4*)(p + 4) = w1;
        }
    }
}

// ---------------------------------------------------------------------------
// Launch
// ---------------------------------------------------------------------------

extern "C" void kernel_launch(void* const* d_in, const int* in_sizes, int n_in,
                              void* d_out, int out_size, void* d_ws, size_t ws_size,
                              hipStream_t stream) {
    const float* x  = (const float*)d_in[0];
    const int*   ei = (const int*)d_in[1];
    const float* W1 = (const float*)d_in[2];
    const float* b1 = (const float*)d_in[3];
    const float* W2 = (const float*)d_in[4];
    const float* b2 = (const float*)d_in[5];

    const int N = in_sizes[0] / C_IN;
    const int E = in_sizes[1] / 2;
    const int* src = ei;
    const int* dst = ei + E;

    char* ws = (char*)d_ws;
    size_t off = 0;
    auto alloc = [&](size_t bytes) -> void* {
        void* p = ws + off;
        off += (bytes + 255) & ~(size_t)255;
        return p;
    };

    int nb   = (N + SCAN_CHUNK - 1) / SCAN_CHUNK;
    int nbkt = (N + BKT_NODES - 1) / BKT_NODES;      // 196 for N=100000 (<=256 req'd)

    int*       counts  = (int*)      alloc((size_t)4 * N);
    int*       rowptr  = (int*)      alloc((size_t)4 * (N + 1));
    float*     dinv    = (float*)    alloc((size_t)4 * N);
    int*       bsum    = (int*)      alloc((size_t)4 * (nb + 1));
    int*       bcursor = (int*)      alloc((size_t)4 * nbkt);
    int*       csr_src = (int*)      alloc((size_t)4 * E);
    _Float16*  W1t     = (_Float16*) alloc((size_t)2 * C_IN * C_HID);
    _Float16*  W2t     = (_Float16*) alloc((size_t)2 * C_HID * C_OUT);
    _Float16*  hmid    = (_Float16*) alloc((size_t)2 * N * C_HID);   // 51.2 MB
    _Float16*  h       = (_Float16*) alloc((size_t)2 * N * C_OUT);
    _Float16*  ybuf0   = (_Float16*) alloc((size_t)2 * N * C_OUT);
    _Float16*  ybuf1   = (_Float16*) alloc((size_t)2 * N * C_OUT);
    _Float16*  ybuf2   = (_Float16*) alloc((size_t)2 * N * C_OUT);

    // bedges (nbkt*BCAP*8B = 38.5 MB) aliases hmid (51.2 MB): all bucket
    // passes complete (in-stream) before k_mlp1 writes hmid.
    long long* bedges = (long long*)hmid;

    // --- CSR build: bucket -> count -> scan -> scatter ---
    hipMemsetAsync(bcursor, 0, (size_t)4 * nbkt, stream);
    k_bucketA<<<(E + EPB - 1) / EPB, 256, 0, stream>>>(src, dst, E, bcursor, bedges, nbkt);
    k_bcount<<<nbkt, 256, 0, stream>>>(bcursor, bedges, counts, N);
    k_dinv<<<(N + 255) / 256, 256, 0, stream>>>(counts, dinv, N);
    k_scan1<<<nb, 256, 0, stream>>>(counts, N, bsum);
    k_scan2<<<1, 64, 0, stream>>>(bsum, nb, E, rowptr, N);
    k_scan3<<<nb, 256, 0, stream>>>(counts, N, bsum, rowptr);
    k_bscatter<<<nbkt, 256, 0, stream>>>(bcursor, bedges, rowptr, csr_src, N);

    // --- weight conversion + MLP (f16 MFMA) ---
    k_w1t<<<(C_IN * C_HID) / 256, 256, 0, stream>>>(W1, W1t);
    k_w2t<<<(C_HID * C_OUT) / 256, 256, 0, stream>>>(W2, W2t);
    k_mlp1<<<(N + 127) / 128, 256, 0, stream>>>(x, W1t, b1, hmid, N);
    k_mlp2<<<(N + 255) / 256, 256, 0, stream>>>(hmid, W2t, b2, dinv, h, ybuf0, N);

    // --- propagation on y; last iteration fuses log_softmax ---
    int pgrid = (N + 3) / 4;
    _Float16* ycur = ybuf0;
    for (int it = 0; it < K_STEPS - 1; ++it) {
        _Float16* ynxt = (it & 1) ? ybuf2 : ybuf1;
        k_prop<false><<<pgrid, 256, 0, stream>>>(rowptr, csr_src, dinv, h, ycur, ynxt, nullptr, N);
        ycur = ynxt;
    }
    k_prop<true><<<pgrid, 256, 0, stream>>>(rowptr, csr_src, dinv, h, ycur, nullptr, (float*)d_out, N);
}